// Round 4
// baseline (22216.353 us; speedup 1.0000x reference)
//
#include <hip/hip_runtime.h>

// LSTM: B=64, T=512, I=256, H=512, L=2, O=128. fp32 in/out, bf16 MFMA compute.
//
// v3: persistent kernel, 128 blocks x 512 threads (8 waves), resident for all
// T=512 steps. Block = (layer = blk>>6, batch-half = (blk>>5)&1, n = blk&31).
// Each block: 32 batches x 16 h-cols (64 packed gate rows). Wave = (nq = N
// half of 32 gate rows, kz = K quarter) -> per-wave weight slice is only
// 12 (L0) / 16 (L1) B-frags = 48/64 VGPRs ==> register-resident (v2 spilled
// at 2x this footprint; VGPR_Count 124 proved it). One f32x16 acc per wave.
// Two counters (cA = layer0 arrivals, cB = layer1), 1 step of skew, deferred
// dout stores after arrive. Same plane parities as harness-verified v1/v2.
//
// ws layout (bytes):
//   0         x_bf16   [64][512][256] bf16   16,777,216
//   16777216  Wpack0   [2048][768]   bf16     3,145,728
//   19922944  Wpack1   [2048][1024]  bf16     4,194,304
//   24117248  h0 planes[2][64][512]  bf16       131,072
//   24248320  h1 planes[2][64][512]  bf16       131,072
//   24379392  cA (u32); 24379392+256 cB (u32)  (zeroed per launch)

#define B_  64
#define T_  512
#define I0_ 256
#define H_  512
#define BH_ (B_ * H_)

typedef unsigned short ushort_t;
typedef __attribute__((ext_vector_type(8)))  short short8;   // 8 bf16 = 4 VGPR
typedef __attribute__((ext_vector_type(16))) float f32x16;   // 32x32 MFMA C/D

__device__ __forceinline__ unsigned short f2bf(float f) {
    unsigned int u = __builtin_bit_cast(unsigned int, f);
    u += 0x7fffu + ((u >> 16) & 1u);           // RTNE
    return (unsigned short)(u >> 16);
}

// ---- prologue: x fp32 -> bf16 -------------------------------------------
__global__ void conv_x(const float* __restrict__ x, ushort_t* __restrict__ xb) {
    size_t i = ((size_t)blockIdx.x * 256 + threadIdx.x) * 4;
    float4 v = *(const float4*)(x + i);
    ushort4 o;
    o.x = f2bf(v.x); o.y = f2bf(v.y); o.z = f2bf(v.z); o.w = f2bf(v.w);
    *(ushort4*)(xb + i) = o;
}

// ---- prologue: pack [W_ih | W_hh] -> bf16, rows grouped per col-group ----
// packed row p = n*64 + strip*16 + jj  ->  gate row g = strip*512 + n*16 + jj
__global__ void pack_w(const float* __restrict__ wih0, const float* __restrict__ whh0,
                       const float* __restrict__ wih1, const float* __restrict__ whh1,
                       ushort_t* __restrict__ wp0, ushort_t* __restrict__ wp1) {
    int p = blockIdx.x;
    int layer = p >> 11;
    int row = p & 2047;
    int n = row >> 6, rem = row & 63;
    int st = rem >> 4, jj = rem & 15;
    int g = st * 512 + n * 16 + jj;
    if (layer == 0) {
        for (int k = threadIdx.x; k < 768; k += 256) {
            float v = (k < 256) ? wih0[(size_t)g * 256 + k]
                                : whh0[(size_t)g * 512 + (k - 256)];
            wp0[(size_t)row * 768 + k] = f2bf(v);
        }
    } else {
        for (int k = threadIdx.x; k < 1024; k += 256) {
            float v = (k < 512) ? wih1[(size_t)g * 512 + k]
                                : whh1[(size_t)g * 512 + (k - 512)];
            wp1[(size_t)row * 1024 + k] = f2bf(v);
        }
    }
}

// ---- prologue: zero h planes + counters ----------------------------------
__global__ void zero_ws(uint4* p) {
    p[(size_t)blockIdx.x * 256 + threadIdx.x] = uint4{0, 0, 0, 0};
}

// ---- persistent kernel ---------------------------------------------------
// step s in [0,512). layer0 computes t=s; layer1 computes t=u-1 at its step u.
// h0: L0 reads plane (s+1)&1, writes plane s&1.
// h1: L1 reads plane u&1, writes plane (u+1)&1; input h_seq0[u-1] = h0 plane (u+1)&1.
// counters: after all 64 L0 blocks finish step s, cA = 64(s+1); L1 likewise cB.
// L0 top-of-step s waits: cA>=64s (recurrence), cB>=64(s-1) (WAR: plane s&1
// holds h0[t=s-2], read by L1 at step s-1). L1 top-of-step u waits: cA>=64u
// (h0[t=u-1] ready), cB>=64(u-1) (own recurrence + WAR).
__global__ __launch_bounds__(512, 1) void lstm_persist(
    const ushort_t* __restrict__ xbf,
    const ushort_t* __restrict__ wp0,
    const ushort_t* __restrict__ wp1,
    ushort_t* __restrict__ h0,
    ushort_t* __restrict__ h1,
    const float* __restrict__ bi0, const float* __restrict__ bh0,
    const float* __restrict__ bi1, const float* __restrict__ bh1,
    float* __restrict__ dout,
    unsigned* __restrict__ barcnt)
{
    __shared__ float xch[2][32][68];   // [fold-half][batch][gate-row], pad 68

    const int blk   = blockIdx.x;
    const int layer = blk >> 6;
    const int half_ = (blk >> 5) & 1;  // batch half
    const int n     = blk & 31;        // h-col group
    const int tid   = threadIdx.x;
    const int lane  = tid & 63;
    const int wv    = tid >> 6;        // 0..7
    const int nq    = wv & 1;          // gate-row half (32 rows)
    const int kz    = wv >> 1;         // K quarter 0..3
    const int c31   = lane & 31;
    const int hi    = lane >> 5;
    const int k8    = hi * 8;          // A/B k sub-offset
    const int bb0   = half_ * 32;      // batch base

    // elementwise mapping: 512 threads -> 32 batches x 16 cols, 1 elem each
    const int jj   = tid & 15;
    const int bloc = tid >> 4;         // 0..31
    const int col  = n * 16 + jj;

    unsigned* cA = barcnt;
    unsigned* cB = barcnt + 64;        // separate cache line (+256 B)

    const float* bip = layer ? bi1 : bi0;
    const float* bhp = layer ? bh1 : bh0;
    const float bI = bip[col]        + bhp[col];
    const float bF = bip[512 + col]  + bhp[512 + col];
    const float bG = bip[1024 + col] + bhp[1024 + col];
    const float bO = bip[1536 + col] + bhp[1536 + col];

    float cr = 0.f;                    // c-state in register all T steps

    if (layer == 0) {
        // B-frags: 12 per wave (K quarter = 192 of 768)
        short8 wf[12];
        {
            const ushort_t* wb = wp0 + (size_t)(n * 64 + nq * 32 + c31) * 768 + kz * 192 + k8;
            #pragma unroll
            for (int kc = 0; kc < 12; ++kc) wf[kc] = *(const short8*)(wb + kc * 16);
        }
        const ushort_t* xrow = xbf + (size_t)(bb0 + c31) * (T_ * I0_);

        for (int s = 0; s < 512; ++s) {
            const unsigned tA = 64u * (unsigned)s;
            const unsigned tB = (s >= 1) ? 64u * (unsigned)(s - 1) : 0u;
            if (tid == 0) {
                if (tA) while (__hip_atomic_load(cA, __ATOMIC_RELAXED, __HIP_MEMORY_SCOPE_AGENT) < tA) { }
                if (tB) while (__hip_atomic_load(cB, __ATOMIC_RELAXED, __HIP_MEMORY_SCOPE_AGENT) < tB) { }
            }
            __syncthreads();
            __threadfence();

            const int rp = (s + 1) & 1;
            const ushort_t* hrow = h0 + rp * BH_ + (size_t)(bb0 + c31) * H_;
            const ushort_t* xr   = xrow + (size_t)s * I0_;

            f32x16 acc = {0.f,0.f,0.f,0.f,0.f,0.f,0.f,0.f,0.f,0.f,0.f,0.f,0.f,0.f,0.f,0.f};
            #pragma unroll
            for (int kc = 0; kc < 12; ++kc) {
                const int K = kz * 192 + kc * 16;
                const ushort_t* ap = (K < 256) ? (xr + K + k8) : (hrow + (K - 256) + k8);
                short8 av = *(const short8*)ap;
                acc = __builtin_amdgcn_mfma_f32_32x32x16_bf16(av, wf[kc], acc, 0, 0, 0);
            }
            // D layout (32x32): col = lane&31 (gate row), row = (r&3)+8*(r>>2)+4*hi (batch)
            if (kz < 2) {
                #pragma unroll
                for (int r = 0; r < 16; ++r) {
                    int brow = (r & 3) + 8 * (r >> 2) + 4 * hi;
                    xch[kz][brow][nq * 32 + c31] = acc[r];
                }
            }
            __syncthreads();
            if (kz >= 2) {
                #pragma unroll
                for (int r = 0; r < 16; ++r) {
                    int brow = (r & 3) + 8 * (r >> 2) + 4 * hi;
                    xch[kz - 2][brow][nq * 32 + c31] += acc[r];
                }
            }
            __syncthreads();

            float iv = xch[0][bloc][jj]      + xch[1][bloc][jj]      + bI;
            float fv = xch[0][bloc][16 + jj] + xch[1][bloc][16 + jj] + bF;
            float gv = xch[0][bloc][32 + jj] + xch[1][bloc][32 + jj] + bG;
            float ov = xch[0][bloc][48 + jj] + xch[1][bloc][48 + jj] + bO;
            float ig = 1.f / (1.f + __expf(-iv));
            float fg = 1.f / (1.f + __expf(-fv));
            float og = 1.f / (1.f + __expf(-ov));
            float cn = fg * cr + ig * tanhf(gv);
            cr = cn;
            float hn = og * tanhf(cn);
            (h0 + (s & 1) * BH_)[(bb0 + bloc) * H_ + col] = f2bf(hn);

            __threadfence();
            __syncthreads();
            if (tid == 0) __hip_atomic_fetch_add(cA, 1u, __ATOMIC_RELEASE, __HIP_MEMORY_SCOPE_AGENT);

            if (s == 511) {                                   // deferred, output-only
                dout[16785408 + (bb0 + bloc) * H_ + col] = hn;   // hidden[0]
                dout[16850944 + (bb0 + bloc) * H_ + col] = cn;   // cell[0]
            }
        }
    } else {
        // B-frags: 16 per wave (K quarter = 256 of 1024)
        short8 wf[16];
        {
            const ushort_t* wb = wp1 + (size_t)(n * 64 + nq * 32 + c31) * 1024 + kz * 256 + k8;
            #pragma unroll
            for (int kc = 0; kc < 16; ++kc) wf[kc] = *(const short8*)(wb + kc * 16);
        }

        for (int u = 1; u <= 512; ++u) {
            const unsigned tA = 64u * (unsigned)u;
            const unsigned tB = (u >= 2) ? 64u * (unsigned)(u - 1) : 0u;
            if (tid == 0) {
                while (__hip_atomic_load(cA, __ATOMIC_RELAXED, __HIP_MEMORY_SCOPE_AGENT) < tA) { }
                if (tB) while (__hip_atomic_load(cB, __ATOMIC_RELAXED, __HIP_MEMORY_SCOPE_AGENT) < tB) { }
            }
            __syncthreads();
            __threadfence();

            const int t  = u - 1;
            const int rp = (u + 1) & 1;
            // kz 0,1: h_seq0[t] = h0 plane rp; kz 2,3: h1[t-1] = h1 plane u&1
            const ushort_t* base = (kz < 2)
                ? (h0 + rp * BH_      + (size_t)(bb0 + c31) * H_ + kz * 256)
                : (h1 + (u & 1) * BH_ + (size_t)(bb0 + c31) * H_ + (kz - 2) * 256);

            f32x16 acc = {0.f,0.f,0.f,0.f,0.f,0.f,0.f,0.f,0.f,0.f,0.f,0.f,0.f,0.f,0.f,0.f};
            #pragma unroll
            for (int kc = 0; kc < 16; ++kc) {
                short8 av = *(const short8*)(base + kc * 16 + k8);
                acc = __builtin_amdgcn_mfma_f32_32x32x16_bf16(av, wf[kc], acc, 0, 0, 0);
            }
            if (kz < 2) {
                #pragma unroll
                for (int r = 0; r < 16; ++r) {
                    int brow = (r & 3) + 8 * (r >> 2) + 4 * hi;
                    xch[kz][brow][nq * 32 + c31] = acc[r];
                }
            }
            __syncthreads();
            if (kz >= 2) {
                #pragma unroll
                for (int r = 0; r < 16; ++r) {
                    int brow = (r & 3) + 8 * (r >> 2) + 4 * hi;
                    xch[kz - 2][brow][nq * 32 + c31] += acc[r];
                }
            }
            __syncthreads();

            float iv = xch[0][bloc][jj]      + xch[1][bloc][jj]      + bI;
            float fv = xch[0][bloc][16 + jj] + xch[1][bloc][16 + jj] + bF;
            float gv = xch[0][bloc][32 + jj] + xch[1][bloc][32 + jj] + bG;
            float ov = xch[0][bloc][48 + jj] + xch[1][bloc][48 + jj] + bO;
            float ig = 1.f / (1.f + __expf(-iv));
            float fg = 1.f / (1.f + __expf(-fv));
            float og = 1.f / (1.f + __expf(-ov));
            float cn = fg * cr + ig * tanhf(gv);
            cr = cn;
            float hn = og * tanhf(cn);
            (h1 + rp * BH_)[(bb0 + bloc) * H_ + col] = f2bf(hn);

            __threadfence();
            __syncthreads();
            if (tid == 0) __hip_atomic_fetch_add(cB, 1u, __ATOMIC_RELEASE, __HIP_MEMORY_SCOPE_AGENT);

            // deferred output-only stores (hidden under the next spin)
            dout[8192 + ((size_t)(bb0 + bloc) * T_ + t) * H_ + col] = hn;   // lstm_out
            if (t == 511) {
                dout[16785408 + BH_ + (bb0 + bloc) * H_ + col] = hn;        // hidden[1]
                dout[16850944 + BH_ + (bb0 + bloc) * H_ + col] = cn;        // cell[1]
            }
        }
    }
}

// ---- final projection: out = h1T @ W_out^T + b_out -----------------------
__global__ void out_gemm(const float* __restrict__ h1T, const float* __restrict__ wout,
                         const float* __restrict__ bout, float* __restrict__ out) {
    int b = blockIdx.x, o = threadIdx.x;
    const float* hr = h1T + (size_t)b * 512;
    const float* wr = wout + (size_t)o * 512;
    float acc = bout[o];
    #pragma unroll 8
    for (int k = 0; k < 512; ++k) acc += hr[k] * wr[k];
    out[b * 128 + o] = acc;
}

extern "C" void kernel_launch(void* const* d_in, const int* in_sizes, int n_in,
                              void* d_out, int out_size, void* d_ws, size_t ws_size,
                              hipStream_t stream)
{
    const float* x    = (const float*)d_in[0];
    const float* wih0 = (const float*)d_in[1];
    const float* whh0 = (const float*)d_in[2];
    const float* bih0 = (const float*)d_in[3];
    const float* bhh0 = (const float*)d_in[4];
    const float* wih1 = (const float*)d_in[5];
    const float* whh1 = (const float*)d_in[6];
    const float* bih1 = (const float*)d_in[7];
    const float* bhh1 = (const float*)d_in[8];
    const float* wout = (const float*)d_in[9];
    const float* bout = (const float*)d_in[10];
    float* out = (float*)d_out;

    char* ws = (char*)d_ws;
    ushort_t* xbf = (ushort_t*)(ws);
    ushort_t* wp0 = (ushort_t*)(ws + 16777216);
    ushort_t* wp1 = (ushort_t*)(ws + 19922944);
    ushort_t* h0  = (ushort_t*)(ws + 24117248);
    ushort_t* h1  = (ushort_t*)(ws + 24248320);
    unsigned* bar = (unsigned*)(ws + 24379392);

    conv_x<<<8192, 256, 0, stream>>>(x, xbf);
    pack_w<<<4096, 256, 0, stream>>>(wih0, whh0, wih1, whh1, wp0, wp1);
    zero_ws<<<128, 256, 0, stream>>>((uint4*)(ws + 24117248));  // h planes + counters

    void* kargs[] = { (void*)&xbf, (void*)&wp0, (void*)&wp1, (void*)&h0, (void*)&h1,
                      (void*)&bih0, (void*)&bhh0, (void*)&bih1, (void*)&bhh1,
                      (void*)&out, (void*)&bar };
    hipError_t ce = hipLaunchCooperativeKernel((const void*)lstm_persist,
                                               dim3(128), dim3(512), kargs, 0u, stream);
    if (ce != hipSuccess) {
        // fallback: plain launch (128 blocks on 256 CUs — co-resident)
        lstm_persist<<<128, 512, 0, stream>>>(xbf, wp0, wp1, h0, h1,
                                              bih0, bhh0, bih1, bhh1, out, bar);
    }

    // hidden[1] = h1T lives at float offset 16785408 + 64*512
    out_gemm<<<64, 128, 0, stream>>>(out + 16785408 + BH_, wout, bout, out);
}

// Round 5
// 5974.593 us; speedup vs baseline: 3.7185x; 3.7185x over previous
//
#include <hip/hip_runtime.h>

// LSTM: B=64, T=512, I=256, H=512, L=2, O=128. fp32 in/out, bf16 MFMA compute.
//
// v4: persistent kernel, 128 blocks x 512 threads. Same decomposition as v3
// (block = layer x batch-half x 16 h-cols; wave = N-half x K-quarter).
// Changes vs v3 (both aimed at measured defects):
//  1. Barrier: per-block FLAG array + leader-scan + TOKEN broadcast, replacing
//     the shared fetch_add counters (v3: 43us/step from hot-line RMW
//     contention). Arrival = 1 release-store to own word; block 0 wave 0
//     scans 128 flags (2/lane); everyone polls one token with s_sleep backoff.
//  2. Weights pinned in VGPRs via inline-asm global_load_dwordx4 (v2/v3:
//     compiler sank the loads into the loop; VGPR_Count 76 proved it).
//  Also: L0 x-fragments prefetched before the token wait; xch is write-only
//  [4][32][68] + single syncthreads (kills the 8.4M LDS RMW conflicts).
//
// ws layout (bytes):
//   0         x_bf16   [64][512][256] bf16   16,777,216
//   16777216  Wpack0   [2048][768]   bf16     3,145,728
//   19922944  Wpack1   [2048][1024]  bf16     4,194,304
//   24117248  h0 planes[2][64][512]  bf16       131,072
//   24248320  h1 planes[2][64][512]  bf16       131,072
//   24379392  flags[128] u32; +1024: token u32   (zeroed per launch)

#define B_  64
#define T_  512
#define I0_ 256
#define H_  512
#define BH_ (B_ * H_)

typedef unsigned short ushort_t;
typedef __attribute__((ext_vector_type(8)))  short short8;   // 8 bf16 = 4 VGPR
typedef __attribute__((ext_vector_type(16))) float f32x16;   // 32x32 MFMA C/D

__device__ __forceinline__ unsigned short f2bf(float f) {
    unsigned int u = __builtin_bit_cast(unsigned int, f);
    u += 0x7fffu + ((u >> 16) & 1u);           // RTNE
    return (unsigned short)(u >> 16);
}

// asm load: result is un-rematerializable -> compiler must keep it in VGPRs.
__device__ __forceinline__ short8 pinned_load(const ushort_t* p) {
    short8 v;
    asm volatile("global_load_dwordx4 %0, %1, off" : "=v"(v) : "v"(p));
    return v;
}

// ---- prologue: x fp32 -> bf16 -------------------------------------------
__global__ void conv_x(const float* __restrict__ x, ushort_t* __restrict__ xb) {
    size_t i = ((size_t)blockIdx.x * 256 + threadIdx.x) * 4;
    float4 v = *(const float4*)(x + i);
    ushort4 o;
    o.x = f2bf(v.x); o.y = f2bf(v.y); o.z = f2bf(v.z); o.w = f2bf(v.w);
    *(ushort4*)(xb + i) = o;
}

// ---- prologue: pack [W_ih | W_hh] -> bf16, rows grouped per col-group ----
// packed row p = n*64 + strip*16 + jj  ->  gate row g = strip*512 + n*16 + jj
__global__ void pack_w(const float* __restrict__ wih0, const float* __restrict__ whh0,
                       const float* __restrict__ wih1, const float* __restrict__ whh1,
                       ushort_t* __restrict__ wp0, ushort_t* __restrict__ wp1) {
    int p = blockIdx.x;
    int layer = p >> 11;
    int row = p & 2047;
    int n = row >> 6, rem = row & 63;
    int st = rem >> 4, jj = rem & 15;
    int g = st * 512 + n * 16 + jj;
    if (layer == 0) {
        for (int k = threadIdx.x; k < 768; k += 256) {
            float v = (k < 256) ? wih0[(size_t)g * 256 + k]
                                : whh0[(size_t)g * 512 + (k - 256)];
            wp0[(size_t)row * 768 + k] = f2bf(v);
        }
    } else {
        for (int k = threadIdx.x; k < 1024; k += 256) {
            float v = (k < 512) ? wih1[(size_t)g * 512 + k]
                                : whh1[(size_t)g * 512 + (k - 512)];
            wp1[(size_t)row * 1024 + k] = f2bf(v);
        }
    }
}

// ---- prologue: zero h planes + flags/token -------------------------------
__global__ void zero_ws(uint4* p) {
    p[(size_t)blockIdx.x * 256 + threadIdx.x] = uint4{0, 0, 0, 0};
}

// ---- flag/token barrier helpers ------------------------------------------
__device__ __forceinline__ void arrive(unsigned* flags, int blk, unsigned r) {
    // __syncthreads() before call drained vmcnt; release store flushes L2.
    __hip_atomic_store(&flags[blk], r, __ATOMIC_RELEASE, __HIP_MEMORY_SCOPE_AGENT);
}

__device__ __forceinline__ void token_wait(const unsigned* tok, unsigned r, int tid) {
    if (tid == 0) {
        while (__hip_atomic_load(tok, __ATOMIC_RELAXED, __HIP_MEMORY_SCOPE_AGENT) < r)
            __builtin_amdgcn_s_sleep(1);
        (void)__hip_atomic_load(tok, __ATOMIC_ACQUIRE, __HIP_MEMORY_SCOPE_AGENT);
    }
    __syncthreads();
}

// leader: block 0 wave 0 scans all 128 flags (2 per lane), publishes token=r.
__device__ __forceinline__ void leader_publish(const unsigned* flags, unsigned* tok,
                                               unsigned r, int tid) {
    if (tid < 64) {
        unsigned v0, v1;
        do {
            v0 = __hip_atomic_load(&flags[tid],      __ATOMIC_RELAXED, __HIP_MEMORY_SCOPE_AGENT);
            v1 = __hip_atomic_load(&flags[64 + tid], __ATOMIC_RELAXED, __HIP_MEMORY_SCOPE_AGENT);
        } while (v0 < r || v1 < r);
        if (tid == 0)
            __hip_atomic_store(tok, r, __ATOMIC_RELEASE, __HIP_MEMORY_SCOPE_AGENT);
    }
}

// ---- persistent kernel ---------------------------------------------------
// Rounds r = 1..512. L0 step s (0..511): needs token>=s, arrives flag=s+1.
// L1 step u (1..512): needs token>=u, arrives flag=u+1 (u<512); initial
// idle arrival flag=1. h0: L0 writes plane s&1; L1 reads plane (u+1)&1
// (= h_seq0[u-1]). h1: L1 reads plane u&1, writes plane (u+1)&1.
__global__ __launch_bounds__(512, 1) void lstm_persist(
    const ushort_t* __restrict__ xbf,
    const ushort_t* __restrict__ wp0,
    const ushort_t* __restrict__ wp1,
    ushort_t* __restrict__ h0,
    ushort_t* __restrict__ h1,
    const float* __restrict__ bi0, const float* __restrict__ bh0,
    const float* __restrict__ bi1, const float* __restrict__ bh1,
    float* __restrict__ dout,
    unsigned* __restrict__ barcnt)
{
    __shared__ float xch[4][32][68];   // [K-quarter][batch][gate-row], pad 68

    const int blk   = blockIdx.x;
    const int layer = blk >> 6;
    const int half_ = (blk >> 5) & 1;  // batch half
    const int n     = blk & 31;        // h-col group
    const int tid   = threadIdx.x;
    const int lane  = tid & 63;
    const int wv    = tid >> 6;        // 0..7
    const int nq    = wv & 1;          // gate-row half (32 rows)
    const int kz    = wv >> 1;         // K quarter 0..3
    const int c31   = lane & 31;
    const int hi    = lane >> 5;
    const int k8    = hi * 8;          // A/B k sub-offset
    const int bb0   = half_ * 32;      // batch base

    const int jj   = tid & 15;
    const int bloc = tid >> 4;         // 0..31
    const int col  = n * 16 + jj;

    unsigned* flags = barcnt;          // [128] u32
    unsigned* tok   = barcnt + 256;    // +1024 B

    const float* bip = layer ? bi1 : bi0;
    const float* bhp = layer ? bh1 : bh0;
    const float bI = bip[col]        + bhp[col];
    const float bF = bip[512 + col]  + bhp[512 + col];
    const float bG = bip[1024 + col] + bhp[1024 + col];
    const float bO = bip[1536 + col] + bhp[1536 + col];

    float cr = 0.f;                    // c-state in register all T steps

    if (layer == 0) {
        // 12 B-frags per wave (K quarter = 192 of 768), pinned via asm loads
        short8 wf[12];
        {
            const ushort_t* wb = wp0 + (size_t)(n * 64 + nq * 32 + c31) * 768 + kz * 192 + k8;
            #pragma unroll
            for (int kc = 0; kc < 12; ++kc) wf[kc] = pinned_load(wb + kc * 16);
            asm volatile("s_waitcnt vmcnt(0)" ::: "memory");
        }
        const ushort_t* xrow = xbf + (size_t)(bb0 + c31) * (T_ * I0_);
        const int nx = (kz == 0) ? 12 : ((kz == 1) ? 4 : 0);   // x-frag count

        for (int s = 0; s < 512; ++s) {
            // prefetch x fragments (barrier-independent) before the wait
            short8 xv[12];
            const ushort_t* xr = xrow + (size_t)s * I0_ + kz * 192 + k8;
            for (int kc = 0; kc < nx; ++kc) xv[kc] = *(const short8*)(xr + kc * 16);

            if (s > 0) token_wait(tok, (unsigned)s, tid);
            else __syncthreads();

            const int rp = (s + 1) & 1;
            const ushort_t* hrow = h0 + rp * BH_ + (size_t)(bb0 + c31) * H_;

            f32x16 acc = {0.f,0.f,0.f,0.f,0.f,0.f,0.f,0.f,0.f,0.f,0.f,0.f,0.f,0.f,0.f,0.f};
            #pragma unroll
            for (int kc = 0; kc < 12; ++kc) {
                const int K = kz * 192 + kc * 16;
                short8 av = (kc < nx) ? xv[kc]
                                      : *(const short8*)(hrow + (K - 256) + k8);
                acc = __builtin_amdgcn_mfma_f32_32x32x16_bf16(av, wf[kc], acc, 0, 0, 0);
            }
            // D: col = lane&31 (gate row), row = (r&3)+8*(r>>2)+4*hi (batch)
            #pragma unroll
            for (int r = 0; r < 16; ++r) {
                int brow = (r & 3) + 8 * (r >> 2) + 4 * hi;
                xch[kz][brow][nq * 32 + c31] = acc[r];
            }
            __syncthreads();

            float iv = xch[0][bloc][jj]      + xch[1][bloc][jj]
                     + xch[2][bloc][jj]      + xch[3][bloc][jj]      + bI;
            float fv = xch[0][bloc][16 + jj] + xch[1][bloc][16 + jj]
                     + xch[2][bloc][16 + jj] + xch[3][bloc][16 + jj] + bF;
            float gv = xch[0][bloc][32 + jj] + xch[1][bloc][32 + jj]
                     + xch[2][bloc][32 + jj] + xch[3][bloc][32 + jj] + bG;
            float ov = xch[0][bloc][48 + jj] + xch[1][bloc][48 + jj]
                     + xch[2][bloc][48 + jj] + xch[3][bloc][48 + jj] + bO;
            float ig = 1.f / (1.f + __expf(-iv));
            float fg = 1.f / (1.f + __expf(-fv));
            float og = 1.f / (1.f + __expf(-ov));
            float cn = fg * cr + ig * tanhf(gv);
            cr = cn;
            float hn = og * tanhf(cn);
            (h0 + (s & 1) * BH_)[(bb0 + bloc) * H_ + col] = f2bf(hn);

            __syncthreads();                       // drains vmcnt before release
            if (tid == 0) arrive(flags, blk, (unsigned)(s + 1));

            if (s == 511) {                        // deferred, output-only
                dout[16785408 + (bb0 + bloc) * H_ + col] = hn;   // hidden[0]
                dout[16850944 + (bb0 + bloc) * H_ + col] = cn;   // cell[0]
            }
            if (blk == 0) leader_publish(flags, tok, (unsigned)(s + 1), tid);
        }
    } else {
        // 16 B-frags per wave (K quarter = 256 of 1024), pinned via asm loads
        short8 wf[16];
        {
            const ushort_t* wb = wp1 + (size_t)(n * 64 + nq * 32 + c31) * 1024 + kz * 256 + k8;
            #pragma unroll
            for (int kc = 0; kc < 16; ++kc) wf[kc] = pinned_load(wb + kc * 16);
            asm volatile("s_waitcnt vmcnt(0)" ::: "memory");
        }

        __syncthreads();
        if (tid == 0) arrive(flags, blk, 1u);      // idle round-1 arrival

        for (int u = 1; u <= 512; ++u) {
            token_wait(tok, (unsigned)u, tid);

            const int t  = u - 1;
            const int rp = (u + 1) & 1;
            // kz 0,1: h_seq0[t] = h0 plane rp; kz 2,3: h1[t-1] = h1 plane u&1
            const ushort_t* base = (kz < 2)
                ? (h0 + rp * BH_      + (size_t)(bb0 + c31) * H_ + kz * 256)
                : (h1 + (u & 1) * BH_ + (size_t)(bb0 + c31) * H_ + (kz - 2) * 256);

            f32x16 acc = {0.f,0.f,0.f,0.f,0.f,0.f,0.f,0.f,0.f,0.f,0.f,0.f,0.f,0.f,0.f,0.f};
            #pragma unroll
            for (int kc = 0; kc < 16; ++kc) {
                short8 av = *(const short8*)(base + kc * 16 + k8);
                acc = __builtin_amdgcn_mfma_f32_32x32x16_bf16(av, wf[kc], acc, 0, 0, 0);
            }
            #pragma unroll
            for (int r = 0; r < 16; ++r) {
                int brow = (r & 3) + 8 * (r >> 2) + 4 * hi;
                xch[kz][brow][nq * 32 + c31] = acc[r];
            }
            __syncthreads();

            float iv = xch[0][bloc][jj]      + xch[1][bloc][jj]
                     + xch[2][bloc][jj]      + xch[3][bloc][jj]      + bI;
            float fv = xch[0][bloc][16 + jj] + xch[1][bloc][16 + jj]
                     + xch[2][bloc][16 + jj] + xch[3][bloc][16 + jj] + bF;
            float gv = xch[0][bloc][32 + jj] + xch[1][bloc][32 + jj]
                     + xch[2][bloc][32 + jj] + xch[3][bloc][32 + jj] + bG;
            float ov = xch[0][bloc][48 + jj] + xch[1][bloc][48 + jj]
                     + xch[2][bloc][48 + jj] + xch[3][bloc][48 + jj] + bO;
            float ig = 1.f / (1.f + __expf(-iv));
            float fg = 1.f / (1.f + __expf(-fv));
            float og = 1.f / (1.f + __expf(-ov));
            float cn = fg * cr + ig * tanhf(gv);
            cr = cn;
            float hn = og * tanhf(cn);
            (h1 + rp * BH_)[(bb0 + bloc) * H_ + col] = f2bf(hn);

            __syncthreads();                       // drains vmcnt before release
            if (u < 512 && tid == 0) arrive(flags, blk, (unsigned)(u + 1));

            // deferred output-only stores (hidden under next token wait)
            dout[8192 + ((size_t)(bb0 + bloc) * T_ + t) * H_ + col] = hn;   // lstm_out
            if (t == 511) {
                dout[16785408 + BH_ + (bb0 + bloc) * H_ + col] = hn;        // hidden[1]
                dout[16850944 + BH_ + (bb0 + bloc) * H_ + col] = cn;        // cell[1]
            }
        }
    }
}

// ---- final projection: out = h1T @ W_out^T + b_out -----------------------
__global__ void out_gemm(const float* __restrict__ h1T, const float* __restrict__ wout,
                         const float* __restrict__ bout, float* __restrict__ out) {
    int b = blockIdx.x, o = threadIdx.x;
    const float* hr = h1T + (size_t)b * 512;
    const float* wr = wout + (size_t)o * 512;
    float acc = bout[o];
    #pragma unroll 8
    for (int k = 0; k < 512; ++k) acc += hr[k] * wr[k];
    out[b * 128 + o] = acc;
}

extern "C" void kernel_launch(void* const* d_in, const int* in_sizes, int n_in,
                              void* d_out, int out_size, void* d_ws, size_t ws_size,
                              hipStream_t stream)
{
    const float* x    = (const float*)d_in[0];
    const float* wih0 = (const float*)d_in[1];
    const float* whh0 = (const float*)d_in[2];
    const float* bih0 = (const float*)d_in[3];
    const float* bhh0 = (const float*)d_in[4];
    const float* wih1 = (const float*)d_in[5];
    const float* whh1 = (const float*)d_in[6];
    const float* bih1 = (const float*)d_in[7];
    const float* bhh1 = (const float*)d_in[8];
    const float* wout = (const float*)d_in[9];
    const float* bout = (const float*)d_in[10];
    float* out = (float*)d_out;

    char* ws = (char*)d_ws;
    ushort_t* xbf = (ushort_t*)(ws);
    ushort_t* wp0 = (ushort_t*)(ws + 16777216);
    ushort_t* wp1 = (ushort_t*)(ws + 19922944);
    ushort_t* h0  = (ushort_t*)(ws + 24117248);
    ushort_t* h1  = (ushort_t*)(ws + 24248320);
    unsigned* bar = (unsigned*)(ws + 24379392);

    conv_x<<<8192, 256, 0, stream>>>(x, xbf);
    pack_w<<<4096, 256, 0, stream>>>(wih0, whh0, wih1, whh1, wp0, wp1);
    zero_ws<<<128, 256, 0, stream>>>((uint4*)(ws + 24117248));  // h planes + flags/token

    void* kargs[] = { (void*)&xbf, (void*)&wp0, (void*)&wp1, (void*)&h0, (void*)&h1,
                      (void*)&bih0, (void*)&bhh0, (void*)&bih1, (void*)&bhh1,
                      (void*)&out, (void*)&bar };
    hipError_t ce = hipLaunchCooperativeKernel((const void*)lstm_persist,
                                               dim3(128), dim3(512), kargs, 0u, stream);
    if (ce != hipSuccess) {
        // fallback: plain launch (128 blocks on 256 CUs — co-resident)
        lstm_persist<<<128, 512, 0, stream>>>(xbf, wp0, wp1, h0, h1,
                                              bih0, bhh0, bih1, bhh1, out, bar);
    }

    // hidden[1] = h1T lives at float offset 16785408 + 64*512
    out_gemm<<<64, 128, 0, stream>>>(out + 16785408 + BH_, wout, bout, out);
}

// Round 7
// 5509.249 us; speedup vs baseline: 4.0326x; 1.0845x over previous
//
#include <hip/hip_runtime.h>

// LSTM: B=64, T=512, I=256, H=512, L=2, O=128. fp32 in/out, bf16 MFMA compute.
//
// v5: persistent kernel, 128 blocks x 512 threads. Decomposition as v4.
// Fixes vs v4 (each aimed at a measured defect):
//  1. xv prefetch loops are fully static per kz (v4: runtime bound nx ->
//     localMem spill; WRITE_SIZE 1.18 GB of scratch traffic, VGPR=64).
//  2. amdgpu_waves_per_eu(2,2): RA budget 256 VGPR/wave (we need 1 block/CU;
//     v4's heuristic pinned 64 and spilled L1's 80-reg working set).
//  3. Barrier: direct per-wave flag poll. Batch halves are independent, so a
//     block waits only on its 64 same-half flags: wave0 polls flags[half*64 +
//     lane] (1 flag/lane, divergent spin + s_sleep), tid0 acquires,
//     syncthreads. Arrive = 1 release store (does the L2 writeback).
//     Removes v4's leader+token second hop.
//
// Round protocol: block round m (L0: m=s in 0..511; L1: m=u in 1..512):
//   wait until all 64 same-half flags >= m; compute; own flag = m+1.
//   L1 posts initial flag=1. WAR/RAW audit: every plane reuse crosses the
//   right flag (see v3/v4 headers; unchanged parities, harness-verified).
//
// ws layout (bytes):
//   0         x_bf16   [64][512][256] bf16   16,777,216
//   16777216  Wpack0   [2048][768]   bf16     3,145,728
//   19922944  Wpack1   [2048][1024]  bf16     4,194,304
//   24117248  h0 planes[2][64][512]  bf16       131,072
//   24248320  h1 planes[2][64][512]  bf16       131,072
//   24379392  flags[128] u32 (idx = half*64 + layer*32 + n; zeroed per launch)

#define B_  64
#define T_  512
#define I0_ 256
#define H_  512
#define BH_ (B_ * H_)

typedef unsigned short ushort_t;
typedef __attribute__((ext_vector_type(8)))  short short8;   // 8 bf16 = 4 VGPR
typedef __attribute__((ext_vector_type(16))) float f32x16;   // 32x32 MFMA C/D

__device__ __forceinline__ unsigned short f2bf(float f) {
    unsigned int u = __builtin_bit_cast(unsigned int, f);
    u += 0x7fffu + ((u >> 16) & 1u);           // RTNE
    return (unsigned short)(u >> 16);
}

// asm load: result is un-rematerializable -> must land in VGPRs at the asm.
__device__ __forceinline__ short8 pinned_load(const ushort_t* p) {
    short8 v;
    asm volatile("global_load_dwordx4 %0, %1, off" : "=v"(v) : "v"(p));
    return v;
}

// ---- prologue: x fp32 -> bf16 -------------------------------------------
__global__ void conv_x(const float* __restrict__ x, ushort_t* __restrict__ xb) {
    size_t i = ((size_t)blockIdx.x * 256 + threadIdx.x) * 4;
    float4 v = *(const float4*)(x + i);
    ushort4 o;
    o.x = f2bf(v.x); o.y = f2bf(v.y); o.z = f2bf(v.z); o.w = f2bf(v.w);
    *(ushort4*)(xb + i) = o;
}

// ---- prologue: pack [W_ih | W_hh] -> bf16, rows grouped per col-group ----
// packed row p = n*64 + strip*16 + jj  ->  gate row g = strip*512 + n*16 + jj
__global__ void pack_w(const float* __restrict__ wih0, const float* __restrict__ whh0,
                       const float* __restrict__ wih1, const float* __restrict__ whh1,
                       ushort_t* __restrict__ wp0, ushort_t* __restrict__ wp1) {
    int p = blockIdx.x;
    int layer = p >> 11;
    int row = p & 2047;
    int n = row >> 6, rem = row & 63;
    int st = rem >> 4, jj = rem & 15;
    int g = st * 512 + n * 16 + jj;
    if (layer == 0) {
        for (int k = threadIdx.x; k < 768; k += 256) {
            float v = (k < 256) ? wih0[(size_t)g * 256 + k]
                                : whh0[(size_t)g * 512 + (k - 256)];
            wp0[(size_t)row * 768 + k] = f2bf(v);
        }
    } else {
        for (int k = threadIdx.x; k < 1024; k += 256) {
            float v = (k < 512) ? wih1[(size_t)g * 512 + k]
                                : whh1[(size_t)g * 512 + (k - 512)];
            wp1[(size_t)row * 1024 + k] = f2bf(v);
        }
    }
}

// ---- prologue: zero h planes + flags -------------------------------------
__global__ void zero_ws(uint4* p) {
    p[(size_t)blockIdx.x * 256 + threadIdx.x] = uint4{0, 0, 0, 0};
}

// ---- barrier helpers ------------------------------------------------------
// arrive: release store (emits L2 writeback first -> h writes reach LLC).
__device__ __forceinline__ void arrive(unsigned* flag, unsigned r) {
    __hip_atomic_store(flag, r, __ATOMIC_RELEASE, __HIP_MEMORY_SCOPE_AGENT);
}

// wait: wave0 lanes each poll one same-half flag; tid0 acquire (L1/L2 inv).
__device__ __forceinline__ void wait_half(const unsigned* flags, unsigned r, int tid) {
    if (tid < 64) {
        const unsigned* fp = flags + tid;
        while (__hip_atomic_load(fp, __ATOMIC_RELAXED, __HIP_MEMORY_SCOPE_AGENT) < r)
            __builtin_amdgcn_s_sleep(1);
        if (tid == 0)
            (void)__hip_atomic_load(fp, __ATOMIC_ACQUIRE, __HIP_MEMORY_SCOPE_AGENT);
    }
    __syncthreads();
}

// ---- persistent kernel ---------------------------------------------------
// h0: L0 step s reads plane (s+1)&1, writes plane s&1.
// h1: L1 step u reads plane u&1, writes plane (u+1)&1; input = h0 plane (u+1)&1.
__global__ void __launch_bounds__(512)
__attribute__((amdgpu_waves_per_eu(2, 2)))
lstm_persist(
    const ushort_t* __restrict__ xbf,
    const ushort_t* __restrict__ wp0,
    const ushort_t* __restrict__ wp1,
    ushort_t* __restrict__ h0,
    ushort_t* __restrict__ h1,
    const float* __restrict__ bi0, const float* __restrict__ bh0,
    const float* __restrict__ bi1, const float* __restrict__ bh1,
    float* __restrict__ dout,
    unsigned* __restrict__ barcnt)
{
    __shared__ float xch[4][32][68];   // [K-quarter][batch][gate-row], pad 68

    const int blk   = blockIdx.x;
    const int layer = blk >> 6;
    const int half_ = (blk >> 5) & 1;  // batch half
    const int n     = blk & 31;        // h-col group
    const int tid   = threadIdx.x;
    const int lane  = tid & 63;
    const int wv    = tid >> 6;        // 0..7
    const int nq    = wv & 1;          // gate-row half (32 rows)
    const int kz    = wv >> 1;         // K quarter 0..3
    const int c31   = lane & 31;
    const int hi    = lane >> 5;
    const int k8    = hi * 8;          // A/B k sub-offset
    const int bb0   = half_ * 32;      // batch base

    const int jj   = tid & 15;
    const int bloc = tid >> 4;         // 0..31
    const int col  = n * 16 + jj;

    unsigned* flags  = barcnt + half_ * 64;             // own half's 64 flags
    unsigned* ownflg = flags + layer * 32 + n;

    const float* bip = layer ? bi1 : bi0;
    const float* bhp = layer ? bh1 : bh0;
    const float bI = bip[col]        + bhp[col];
    const float bF = bip[512 + col]  + bhp[512 + col];
    const float bG = bip[1024 + col] + bhp[1024 + col];
    const float bO = bip[1536 + col] + bhp[1536 + col];

    float cr = 0.f;                    // c-state in register all T steps

    if (layer == 0) {
        // 12 B-frags per wave (K quarter = 192 of 768), pinned via asm loads
        short8 wf[12];
        {
            const ushort_t* wb = wp0 + (size_t)(n * 64 + nq * 32 + c31) * 768 + kz * 192 + k8;
            #pragma unroll
            for (int kc = 0; kc < 12; ++kc) wf[kc] = pinned_load(wb + kc * 16);
            asm volatile("s_waitcnt vmcnt(0)" ::: "memory");
        }
        const ushort_t* xrow = xbf + (size_t)(bb0 + c31) * (T_ * I0_);

        for (int s = 0; s < 512; ++s) {
            // prefetch x fragments (barrier-independent); fully static per kz
            short8 xv[12];
            const ushort_t* xr = xrow + (size_t)s * I0_ + kz * 192 + k8;
            if (kz == 0) {
                #pragma unroll
                for (int kc = 0; kc < 12; ++kc) xv[kc] = *(const short8*)(xr + kc * 16);
            } else if (kz == 1) {
                #pragma unroll
                for (int kc = 0; kc < 4; ++kc) xv[kc] = *(const short8*)(xr + kc * 16);
            }

            if (s > 0) wait_half(flags, (unsigned)s, tid);
            else __syncthreads();

            const int rp = (s + 1) & 1;
            const ushort_t* hrow = h0 + rp * BH_ + (size_t)(bb0 + c31) * H_;

            f32x16 acc = {0.f,0.f,0.f,0.f,0.f,0.f,0.f,0.f,0.f,0.f,0.f,0.f,0.f,0.f,0.f,0.f};
            if (kz == 0) {
                #pragma unroll
                for (int kc = 0; kc < 12; ++kc)
                    acc = __builtin_amdgcn_mfma_f32_32x32x16_bf16(xv[kc], wf[kc], acc, 0, 0, 0);
            } else if (kz == 1) {
                #pragma unroll
                for (int kc = 0; kc < 4; ++kc)
                    acc = __builtin_amdgcn_mfma_f32_32x32x16_bf16(xv[kc], wf[kc], acc, 0, 0, 0);
                #pragma unroll
                for (int kc = 4; kc < 12; ++kc) {
                    short8 av = *(const short8*)(hrow + (192 + kc * 16 - 256) + k8);
                    acc = __builtin_amdgcn_mfma_f32_32x32x16_bf16(av, wf[kc], acc, 0, 0, 0);
                }
            } else {
                #pragma unroll
                for (int kc = 0; kc < 12; ++kc) {
                    short8 av = *(const short8*)(hrow + (kz * 192 + kc * 16 - 256) + k8);
                    acc = __builtin_amdgcn_mfma_f32_32x32x16_bf16(av, wf[kc], acc, 0, 0, 0);
                }
            }
            // D: col = lane&31 (gate row), row = (r&3)+8*(r>>2)+4*hi (batch)
            #pragma unroll
            for (int r = 0; r < 16; ++r) {
                int brow = (r & 3) + 8 * (r >> 2) + 4 * hi;
                xch[kz][brow][nq * 32 + c31] = acc[r];
            }
            __syncthreads();

            float iv = xch[0][bloc][jj]      + xch[1][bloc][jj]
                     + xch[2][bloc][jj]      + xch[3][bloc][jj]      + bI;
            float fv = xch[0][bloc][16 + jj] + xch[1][bloc][16 + jj]
                     + xch[2][bloc][16 + jj] + xch[3][bloc][16 + jj] + bF;
            float gv = xch[0][bloc][32 + jj] + xch[1][bloc][32 + jj]
                     + xch[2][bloc][32 + jj] + xch[3][bloc][32 + jj] + bG;
            float ov = xch[0][bloc][48 + jj] + xch[1][bloc][48 + jj]
                     + xch[2][bloc][48 + jj] + xch[3][bloc][48 + jj] + bO;
            float ig = 1.f / (1.f + __expf(-iv));
            float fg = 1.f / (1.f + __expf(-fv));
            float og = 1.f / (1.f + __expf(-ov));
            float cn = fg * cr + ig * tanhf(gv);
            cr = cn;
            float hn = og * tanhf(cn);
            (h0 + (s & 1) * BH_)[(bb0 + bloc) * H_ + col] = f2bf(hn);

            __syncthreads();                       // all waves' stores vmcnt-drained
            if (tid == 0) arrive(ownflg, (unsigned)(s + 1));

            if (s == 511) {                        // deferred, output-only
                dout[16785408 + (bb0 + bloc) * H_ + col] = hn;   // hidden[0]
                dout[16850944 + (bb0 + bloc) * H_ + col] = cn;   // cell[0]
            }
        }
    } else {
        // 16 B-frags per wave (K quarter = 256 of 1024), pinned via asm loads
        short8 wf[16];
        {
            const ushort_t* wb = wp1 + (size_t)(n * 64 + nq * 32 + c31) * 1024 + kz * 256 + k8;
            #pragma unroll
            for (int kc = 0; kc < 16; ++kc) wf[kc] = pinned_load(wb + kc * 16);
            asm volatile("s_waitcnt vmcnt(0)" ::: "memory");
        }

        __syncthreads();
        if (tid == 0) arrive(ownflg, 1u);          // idle round-1 arrival

        for (int u = 1; u <= 512; ++u) {
            wait_half(flags, (unsigned)u, tid);

            const int t  = u - 1;
            const int rp = (u + 1) & 1;
            // kz 0,1: h_seq0[t] = h0 plane rp; kz 2,3: h1[t-1] = h1 plane u&1
            const ushort_t* base = (kz < 2)
                ? (h0 + rp * BH_      + (size_t)(bb0 + c31) * H_ + kz * 256)
                : (h1 + (u & 1) * BH_ + (size_t)(bb0 + c31) * H_ + (kz - 2) * 256);

            f32x16 acc = {0.f,0.f,0.f,0.f,0.f,0.f,0.f,0.f,0.f,0.f,0.f,0.f,0.f,0.f,0.f,0.f};
            #pragma unroll
            for (int kc = 0; kc < 16; ++kc) {
                short8 av = *(const short8*)(base + kc * 16 + k8);
                acc = __builtin_amdgcn_mfma_f32_32x32x16_bf16(av, wf[kc], acc, 0, 0, 0);
            }
            #pragma unroll
            for (int r = 0; r < 16; ++r) {
                int brow = (r & 3) + 8 * (r >> 2) + 4 * hi;
                xch[kz][brow][nq * 32 + c31] = acc[r];
            }
            __syncthreads();

            float iv = xch[0][bloc][jj]      + xch[1][bloc][jj]
                     + xch[2][bloc][jj]      + xch[3][bloc][jj]      + bI;
            float fv = xch[0][bloc][16 + jj] + xch[1][bloc][16 + jj]
                     + xch[2][bloc][16 + jj] + xch[3][bloc][16 + jj] + bF;
            float gv = xch[0][bloc][32 + jj] + xch[1][bloc][32 + jj]
                     + xch[2][bloc][32 + jj] + xch[3][bloc][32 + jj] + bG;
            float ov = xch[0][bloc][48 + jj] + xch[1][bloc][48 + jj]
                     + xch[2][bloc][48 + jj] + xch[3][bloc][48 + jj] + bO;
            float ig = 1.f / (1.f + __expf(-iv));
            float fg = 1.f / (1.f + __expf(-fv));
            float og = 1.f / (1.f + __expf(-ov));
            float cn = fg * cr + ig * tanhf(gv);
            cr = cn;
            float hn = og * tanhf(cn);
            (h1 + rp * BH_)[(bb0 + bloc) * H_ + col] = f2bf(hn);

            __syncthreads();                       // all waves' stores vmcnt-drained
            if (u < 512 && tid == 0) arrive(ownflg, (unsigned)(u + 1));

            // deferred output-only stores (hidden under next wait)
            dout[8192 + ((size_t)(bb0 + bloc) * T_ + t) * H_ + col] = hn;   // lstm_out
            if (t == 511) {
                dout[16785408 + BH_ + (bb0 + bloc) * H_ + col] = hn;        // hidden[1]
                dout[16850944 + BH_ + (bb0 + bloc) * H_ + col] = cn;        // cell[1]
            }
        }
    }
}

// ---- final projection: out = h1T @ W_out^T + b_out -----------------------
__global__ void out_gemm(const float* __restrict__ h1T, const float* __restrict__ wout,
                         const float* __restrict__ bout, float* __restrict__ out) {
    int b = blockIdx.x, o = threadIdx.x;
    const float* hr = h1T + (size_t)b * 512;
    const float* wr = wout + (size_t)o * 512;
    float acc = bout[o];
    #pragma unroll 8
    for (int k = 0; k < 512; ++k) acc += hr[k] * wr[k];
    out[b * 128 + o] = acc;
}

extern "C" void kernel_launch(void* const* d_in, const int* in_sizes, int n_in,
                              void* d_out, int out_size, void* d_ws, size_t ws_size,
                              hipStream_t stream)
{
    const float* x    = (const float*)d_in[0];
    const float* wih0 = (const float*)d_in[1];
    const float* whh0 = (const float*)d_in[2];
    const float* bih0 = (const float*)d_in[3];
    const float* bhh0 = (const float*)d_in[4];
    const float* wih1 = (const float*)d_in[5];
    const float* whh1 = (const float*)d_in[6];
    const float* bih1 = (const float*)d_in[7];
    const float* bhh1 = (const float*)d_in[8];
    const float* wout = (const float*)d_in[9];
    const float* bout = (const float*)d_in[10];
    float* out = (float*)d_out;

    char* ws = (char*)d_ws;
    ushort_t* xbf = (ushort_t*)(ws);
    ushort_t* wp0 = (ushort_t*)(ws + 16777216);
    ushort_t* wp1 = (ushort_t*)(ws + 19922944);
    ushort_t* h0  = (ushort_t*)(ws + 24117248);
    ushort_t* h1  = (ushort_t*)(ws + 24248320);
    unsigned* bar = (unsigned*)(ws + 24379392);

    conv_x<<<8192, 256, 0, stream>>>(x, xbf);
    pack_w<<<4096, 256, 0, stream>>>(wih0, whh0, wih1, whh1, wp0, wp1);
    zero_ws<<<128, 256, 0, stream>>>((uint4*)(ws + 24117248));  // h planes + flags

    void* kargs[] = { (void*)&xbf, (void*)&wp0, (void*)&wp1, (void*)&h0, (void*)&h1,
                      (void*)&bih0, (void*)&bhh0, (void*)&bih1, (void*)&bhh1,
                      (void*)&out, (void*)&bar };
    hipError_t ce = hipLaunchCooperativeKernel((const void*)lstm_persist,
                                               dim3(128), dim3(512), kargs, 0u, stream);
    if (ce != hipSuccess) {
        // fallback: plain launch (128 blocks on 256 CUs — co-resident)
        lstm_persist<<<128, 512, 0, stream>>>(xbf, wp0, wp1, h0, h1,
                                              bih0, bhh0, bih1, bhh1, out, bar);
    }

    // hidden[1] = h1T lives at float offset 16785408 + 64*512
    out_gemm<<<64, 128, 0, stream>>>(out + 16785408 + BH_, wout, bout, out);
}

// Round 9
// 3808.517 us; speedup vs baseline: 5.8333x; 1.4466x over previous
//
#include <hip/hip_runtime.h>

// LSTM: B=64, T=512, I=256, H=512, L=2, O=128. fp32 in/out, bf16 MFMA compute.
//
// v6b: persistent kernel, 128 blocks x 512 threads. Decomposition as v5.
// Changes vs v5 (aimed at the measured coherence overhead: per-round
// wbl2/inv + lock-step coupling; FETCH 657KB/step of HBM refetch):
//  1. All h0/h1 plane accesses are LLC-direct (inline-asm sc0 sc1 load/store,
//     bypassing L1+L2). No stale-copy hazard -> NO acquire-invalidate, NO
//     release-writeback. Arrive = vmcnt drain (via syncthreads) + RELAXED
//     flag store. x + weights stay normally cached and are never invalidated.
//  2. h0 is a 4-plane ring -> L0 may run 2 rounds ahead of L1:
//     L0@s waits: L0 flags >= s, L1 flags >= s-2.
//     L1@u waits: L0 flags >= u, L1 flags >= u  (posts initial flag=1!).
//     Audit: L0@s RAW h0[(s-1)&3] -> L0>=s. WAR plane s&3 (held h0[s-4],
//     read by L0@s-3, L1@s-3 which posts s-2) -> L1>=s-2. L1@u RAW
//     h0[(u-1)&3] -> L0>=u; RAW h1 plane u&1 (peers@u-1 post u) + WAR plane
//     (u+1)&1 -> L1>=u. v6 DEADLOCKED here: without the initial arrival,
//     L1@1's wait for L1>=1 can never be satisfied (audit r8). Fixed.
//  3. Rule-18: asm loads -> s_waitcnt vmcnt(0) -> sched_barrier(0) -> MFMA.
//
// ws layout (bytes):
//   0         x_bf16   [64][512][256] bf16   16,777,216
//   16777216  Wpack0   [2048][768]   bf16     3,145,728
//   19922944  Wpack1   [2048][1024]  bf16     4,194,304
//   24117248  h0 ring  [4][64][512]  bf16       262,144
//   24379392  h1 planes[2][64][512]  bf16       131,072
//   24510464  flags[128] u32 (idx = half*64 + layer*32 + n; zeroed per launch)

#define B_  64
#define T_  512
#define I0_ 256
#define H_  512
#define BH_ (B_ * H_)

typedef unsigned short ushort_t;
typedef __attribute__((ext_vector_type(8)))  short short8;   // 8 bf16 = 4 VGPR
typedef __attribute__((ext_vector_type(16))) float f32x16;   // 32x32 MFMA C/D

__device__ __forceinline__ unsigned short f2bf(float f) {
    unsigned int u = __builtin_bit_cast(unsigned int, f);
    u += 0x7fffu + ((u >> 16) & 1u);           // RTNE
    return (unsigned short)(u >> 16);
}

// asm load: un-rematerializable -> stays in VGPRs (weights).
__device__ __forceinline__ short8 pinned_load(const ushort_t* p) {
    short8 v;
    asm volatile("global_load_dwordx4 %0, %1, off" : "=v"(v) : "v"(p));
    return v;
}
// LLC-direct 16B load (bypass L1+L2; coherent at LLC). Consumer MUST be
// after s_waitcnt vmcnt(0) + sched_barrier(0)  [rule #18].
__device__ __forceinline__ short8 llc_load16(const ushort_t* p) {
    short8 v;
    asm volatile("global_load_dwordx4 %0, %1, off sc0 sc1" : "=v"(v) : "v"(p));
    return v;
}
// LLC-direct 2B store (write-through to LLC).
__device__ __forceinline__ void llc_store2(ushort_t* p, unsigned v) {
    asm volatile("global_store_short %0, %1, off sc0 sc1" :: "v"(p), "v"(v) : "memory");
}

// ---- prologue: x fp32 -> bf16 -------------------------------------------
__global__ void conv_x(const float* __restrict__ x, ushort_t* __restrict__ xb) {
    size_t i = ((size_t)blockIdx.x * 256 + threadIdx.x) * 4;
    float4 v = *(const float4*)(x + i);
    ushort4 o;
    o.x = f2bf(v.x); o.y = f2bf(v.y); o.z = f2bf(v.z); o.w = f2bf(v.w);
    *(ushort4*)(xb + i) = o;
}

// ---- prologue: pack [W_ih | W_hh] -> bf16, rows grouped per col-group ----
// packed row p = n*64 + strip*16 + jj  ->  gate row g = strip*512 + n*16 + jj
__global__ void pack_w(const float* __restrict__ wih0, const float* __restrict__ whh0,
                       const float* __restrict__ wih1, const float* __restrict__ whh1,
                       ushort_t* __restrict__ wp0, ushort_t* __restrict__ wp1) {
    int p = blockIdx.x;
    int layer = p >> 11;
    int row = p & 2047;
    int n = row >> 6, rem = row & 63;
    int st = rem >> 4, jj = rem & 15;
    int g = st * 512 + n * 16 + jj;
    if (layer == 0) {
        for (int k = threadIdx.x; k < 768; k += 256) {
            float v = (k < 256) ? wih0[(size_t)g * 256 + k]
                                : whh0[(size_t)g * 512 + (k - 256)];
            wp0[(size_t)row * 768 + k] = f2bf(v);
        }
    } else {
        for (int k = threadIdx.x; k < 1024; k += 256) {
            float v = (k < 512) ? wih1[(size_t)g * 512 + k]
                                : whh1[(size_t)g * 512 + (k - 512)];
            wp1[(size_t)row * 1024 + k] = f2bf(v);
        }
    }
}

// ---- prologue: zero h ring/planes + flags --------------------------------
__global__ void zero_ws(uint4* p) {
    p[(size_t)blockIdx.x * 256 + threadIdx.x] = uint4{0, 0, 0, 0};
}

// ---- barrier helpers ------------------------------------------------------
// arrive: preceding __syncthreads drained every wave's vmcnt (h stores are
// sc1 write-through -> already at LLC). Relaxed store suffices.
__device__ __forceinline__ void arrive(unsigned* flag, unsigned r) {
    __hip_atomic_store(flag, r, __ATOMIC_RELAXED, __HIP_MEMORY_SCOPE_AGENT);
}

// wait: wave0 lanes 0-31 poll own-layer flags vs tSelf, lanes 32-63 poll
// other-layer flags vs tOther. No acquire needed (h reads are LLC-direct).
__device__ __forceinline__ void wait2(const unsigned* fSelf, const unsigned* fOther,
                                      unsigned tSelf, unsigned tOther, int tid) {
    if (tid < 64) {
        const unsigned* fp = (tid < 32) ? (fSelf + tid) : (fOther + (tid - 32));
        const unsigned tgt = (tid < 32) ? tSelf : tOther;
        while (__hip_atomic_load(fp, __ATOMIC_RELAXED, __HIP_MEMORY_SCOPE_AGENT) < tgt)
            __builtin_amdgcn_s_sleep(1);
    }
    __syncthreads();
    asm volatile("" ::: "memory");
}

// ---- persistent kernel ---------------------------------------------------
// h0 ring: L0@s reads plane (s-1)&3 (s=0 -> plane 3, zeroed), writes s&3.
// h1: L1@u reads plane u&1, writes (u+1)&1; input h_seq0[u-1] = h0 plane (u-1)&3.
__global__ void __launch_bounds__(512)
__attribute__((amdgpu_waves_per_eu(2, 2)))
lstm_persist(
    const ushort_t* __restrict__ xbf,
    const ushort_t* __restrict__ wp0,
    const ushort_t* __restrict__ wp1,
    ushort_t* __restrict__ h0,
    ushort_t* __restrict__ h1,
    const float* __restrict__ bi0, const float* __restrict__ bh0,
    const float* __restrict__ bi1, const float* __restrict__ bh1,
    float* __restrict__ dout,
    unsigned* __restrict__ barcnt)
{
    __shared__ float xch[4][32][68];   // [K-quarter][batch][gate-row], pad 68

    const int blk   = blockIdx.x;
    const int layer = blk >> 6;
    const int half_ = (blk >> 5) & 1;  // batch half
    const int n     = blk & 31;        // h-col group
    const int tid   = threadIdx.x;
    const int lane  = tid & 63;
    const int wv    = tid >> 6;        // 0..7
    const int nq    = wv & 1;          // gate-row half (32 rows)
    const int kz    = wv >> 1;         // K quarter 0..3
    const int c31   = lane & 31;
    const int hi    = lane >> 5;
    const int k8    = hi * 8;          // A/B k sub-offset
    const int bb0   = half_ * 32;      // batch base

    const int jj   = tid & 15;
    const int bloc = tid >> 4;         // 0..31
    const int col  = n * 16 + jj;

    unsigned* fBase  = barcnt + half_ * 64;
    unsigned* fSelf  = fBase + layer * 32;
    unsigned* fOther = fBase + (1 - layer) * 32;
    unsigned* ownflg = fSelf + n;

    const float* bip = layer ? bi1 : bi0;
    const float* bhp = layer ? bh1 : bh0;
    const float bI = bip[col]        + bhp[col];
    const float bF = bip[512 + col]  + bhp[512 + col];
    const float bG = bip[1024 + col] + bhp[1024 + col];
    const float bO = bip[1536 + col] + bhp[1536 + col];

    float cr = 0.f;                    // c-state in register all T steps

    if (layer == 0) {
        // 12 B-frags per wave (K quarter = 192 of 768), pinned via asm loads
        short8 wf[12];
        {
            const ushort_t* wb = wp0 + (size_t)(n * 64 + nq * 32 + c31) * 768 + kz * 192 + k8;
            #pragma unroll
            for (int kc = 0; kc < 12; ++kc) wf[kc] = pinned_load(wb + kc * 16);
            asm volatile("s_waitcnt vmcnt(0)" ::: "memory");
        }
        const ushort_t* xrow = xbf + (size_t)(bb0 + c31) * (T_ * I0_);

        for (int s = 0; s < 512; ++s) {
            // prefetch x fragments (normal cached loads; barrier-independent)
            short8 xv[12];
            const ushort_t* xr = xrow + (size_t)s * I0_ + kz * 192 + k8;
            if (kz == 0) {
                #pragma unroll
                for (int kc = 0; kc < 12; ++kc) xv[kc] = *(const short8*)(xr + kc * 16);
            } else if (kz == 1) {
                #pragma unroll
                for (int kc = 0; kc < 4; ++kc) xv[kc] = *(const short8*)(xr + kc * 16);
            }

            wait2(fSelf, fOther, (unsigned)s, (s >= 2) ? (unsigned)(s - 2) : 0u, tid);

            const ushort_t* hrow = h0 + ((s - 1) & 3) * BH_ + (size_t)(bb0 + c31) * H_;

            f32x16 acc = {0.f,0.f,0.f,0.f,0.f,0.f,0.f,0.f,0.f,0.f,0.f,0.f,0.f,0.f,0.f,0.f};
            if (kz == 0) {
                #pragma unroll
                for (int kc = 0; kc < 12; ++kc)
                    acc = __builtin_amdgcn_mfma_f32_32x32x16_bf16(xv[kc], wf[kc], acc, 0, 0, 0);
            } else if (kz == 1) {
                short8 hv[8];
                #pragma unroll
                for (int kc = 0; kc < 8; ++kc)
                    hv[kc] = llc_load16(hrow + (192 + (kc + 4) * 16 - 256) + k8);
                asm volatile("s_waitcnt vmcnt(0)" ::: "memory");
                __builtin_amdgcn_sched_barrier(0);
                #pragma unroll
                for (int kc = 0; kc < 4; ++kc)
                    acc = __builtin_amdgcn_mfma_f32_32x32x16_bf16(xv[kc], wf[kc], acc, 0, 0, 0);
                #pragma unroll
                for (int kc = 0; kc < 8; ++kc)
                    acc = __builtin_amdgcn_mfma_f32_32x32x16_bf16(hv[kc], wf[kc + 4], acc, 0, 0, 0);
            } else {
                short8 hv[12];
                #pragma unroll
                for (int kc = 0; kc < 12; ++kc)
                    hv[kc] = llc_load16(hrow + (kz * 192 + kc * 16 - 256) + k8);
                asm volatile("s_waitcnt vmcnt(0)" ::: "memory");
                __builtin_amdgcn_sched_barrier(0);
                #pragma unroll
                for (int kc = 0; kc < 12; ++kc)
                    acc = __builtin_amdgcn_mfma_f32_32x32x16_bf16(hv[kc], wf[kc], acc, 0, 0, 0);
            }
            // D: col = lane&31 (gate row), row = (r&3)+8*(r>>2)+4*hi (batch)
            #pragma unroll
            for (int r = 0; r < 16; ++r) {
                int brow = (r & 3) + 8 * (r >> 2) + 4 * hi;
                xch[kz][brow][nq * 32 + c31] = acc[r];
            }
            __syncthreads();

            float iv = xch[0][bloc][jj]      + xch[1][bloc][jj]
                     + xch[2][bloc][jj]      + xch[3][bloc][jj]      + bI;
            float fv = xch[0][bloc][16 + jj] + xch[1][bloc][16 + jj]
                     + xch[2][bloc][16 + jj] + xch[3][bloc][16 + jj] + bF;
            float gv = xch[0][bloc][32 + jj] + xch[1][bloc][32 + jj]
                     + xch[2][bloc][32 + jj] + xch[3][bloc][32 + jj] + bG;
            float ov = xch[0][bloc][48 + jj] + xch[1][bloc][48 + jj]
                     + xch[2][bloc][48 + jj] + xch[3][bloc][48 + jj] + bO;
            float ig = 1.f / (1.f + __expf(-iv));
            float fg = 1.f / (1.f + __expf(-fv));
            float og = 1.f / (1.f + __expf(-ov));
            float cn = fg * cr + ig * tanhf(gv);
            cr = cn;
            float hn = og * tanhf(cn);
            llc_store2(h0 + (s & 3) * BH_ + (bb0 + bloc) * H_ + col,
                       (unsigned)f2bf(hn));

            __syncthreads();                       // drains every wave's vmcnt
            if (tid == 0) arrive(ownflg, (unsigned)(s + 1));

            if (s == 511) {                        // deferred, output-only
                dout[16785408 + (bb0 + bloc) * H_ + col] = hn;   // hidden[0]
                dout[16850944 + (bb0 + bloc) * H_ + col] = cn;   // cell[0]
            }
        }
    } else {
        // 16 B-frags per wave (K quarter = 256 of 1024), pinned via asm loads
        short8 wf[16];
        {
            const ushort_t* wb = wp1 + (size_t)(n * 64 + nq * 32 + c31) * 1024 + kz * 256 + k8;
            #pragma unroll
            for (int kc = 0; kc < 16; ++kc) wf[kc] = pinned_load(wb + kc * 16);
            asm volatile("s_waitcnt vmcnt(0)" ::: "memory");
        }

        __syncthreads();
        if (tid == 0) arrive(ownflg, 1u);          // initial arrival (deadlock fix)

        for (int u = 1; u <= 512; ++u) {
            wait2(fSelf, fOther, (unsigned)u, (unsigned)u, tid);

            const int t  = u - 1;
            // kz 0,1: h_seq0[t] = h0 plane (u-1)&3; kz 2,3: h1[t-1] = h1 plane u&1
            const ushort_t* base = (kz < 2)
                ? (h0 + ((u - 1) & 3) * BH_ + (size_t)(bb0 + c31) * H_ + kz * 256)
                : (h1 + (u & 1) * BH_      + (size_t)(bb0 + c31) * H_ + (kz - 2) * 256);

            short8 hv[16];
            #pragma unroll
            for (int kc = 0; kc < 16; ++kc)
                hv[kc] = llc_load16(base + kc * 16 + k8);
            asm volatile("s_waitcnt vmcnt(0)" ::: "memory");
            __builtin_amdgcn_sched_barrier(0);

            f32x16 acc = {0.f,0.f,0.f,0.f,0.f,0.f,0.f,0.f,0.f,0.f,0.f,0.f,0.f,0.f,0.f,0.f};
            #pragma unroll
            for (int kc = 0; kc < 16; ++kc)
                acc = __builtin_amdgcn_mfma_f32_32x32x16_bf16(hv[kc], wf[kc], acc, 0, 0, 0);
            #pragma unroll
            for (int r = 0; r < 16; ++r) {
                int brow = (r & 3) + 8 * (r >> 2) + 4 * hi;
                xch[kz][brow][nq * 32 + c31] = acc[r];
            }
            __syncthreads();

            float iv = xch[0][bloc][jj]      + xch[1][bloc][jj]
                     + xch[2][bloc][jj]      + xch[3][bloc][jj]      + bI;
            float fv = xch[0][bloc][16 + jj] + xch[1][bloc][16 + jj]
                     + xch[2][bloc][16 + jj] + xch[3][bloc][16 + jj] + bF;
            float gv = xch[0][bloc][32 + jj] + xch[1][bloc][32 + jj]
                     + xch[2][bloc][32 + jj] + xch[3][bloc][32 + jj] + bG;
            float ov = xch[0][bloc][48 + jj] + xch[1][bloc][48 + jj]
                     + xch[2][bloc][48 + jj] + xch[3][bloc][48 + jj] + bO;
            float ig = 1.f / (1.f + __expf(-iv));
            float fg = 1.f / (1.f + __expf(-fv));
            float og = 1.f / (1.f + __expf(-ov));
            float cn = fg * cr + ig * tanhf(gv);
            cr = cn;
            float hn = og * tanhf(cn);
            llc_store2(h1 + ((u + 1) & 1) * BH_ + (bb0 + bloc) * H_ + col,
                       (unsigned)f2bf(hn));

            __syncthreads();                       // drains every wave's vmcnt
            if (u < 512 && tid == 0) arrive(ownflg, (unsigned)(u + 1));

            // deferred output-only stores (hidden under next wait)
            dout[8192 + ((size_t)(bb0 + bloc) * T_ + t) * H_ + col] = hn;   // lstm_out
            if (t == 511) {
                dout[16785408 + BH_ + (bb0 + bloc) * H_ + col] = hn;        // hidden[1]
                dout[16850944 + BH_ + (bb0 + bloc) * H_ + col] = cn;        // cell[1]
            }
        }
    }
}

// ---- final projection: out = h1T @ W_out^T + b_out -----------------------
__global__ void out_gemm(const float* __restrict__ h1T, const float* __restrict__ wout,
                         const float* __restrict__ bout, float* __restrict__ out) {
    int b = blockIdx.x, o = threadIdx.x;
    const float* hr = h1T + (size_t)b * 512;
    const float* wr = wout + (size_t)o * 512;
    float acc = bout[o];
    #pragma unroll 8
    for (int k = 0; k < 512; ++k) acc += hr[k] * wr[k];
    out[b * 128 + o] = acc;
}

extern "C" void kernel_launch(void* const* d_in, const int* in_sizes, int n_in,
                              void* d_out, int out_size, void* d_ws, size_t ws_size,
                              hipStream_t stream)
{
    const float* x    = (const float*)d_in[0];
    const float* wih0 = (const float*)d_in[1];
    const float* whh0 = (const float*)d_in[2];
    const float* bih0 = (const float*)d_in[3];
    const float* bhh0 = (const float*)d_in[4];
    const float* wih1 = (const float*)d_in[5];
    const float* whh1 = (const float*)d_in[6];
    const float* bih1 = (const float*)d_in[7];
    const float* bhh1 = (const float*)d_in[8];
    const float* wout = (const float*)d_in[9];
    const float* bout = (const float*)d_in[10];
    float* out = (float*)d_out;

    char* ws = (char*)d_ws;
    ushort_t* xbf = (ushort_t*)(ws);
    ushort_t* wp0 = (ushort_t*)(ws + 16777216);
    ushort_t* wp1 = (ushort_t*)(ws + 19922944);
    ushort_t* h0  = (ushort_t*)(ws + 24117248);   // 4-plane ring, 262144 B
    ushort_t* h1  = (ushort_t*)(ws + 24379392);   // 2 planes, 131072 B
    unsigned* bar = (unsigned*)(ws + 24510464);   // flags[128]

    conv_x<<<8192, 256, 0, stream>>>(x, xbf);
    pack_w<<<4096, 256, 0, stream>>>(wih0, whh0, wih1, whh1, wp0, wp1);
    zero_ws<<<128, 256, 0, stream>>>((uint4*)(ws + 24117248));  // h ring/planes + flags

    void* kargs[] = { (void*)&xbf, (void*)&wp0, (void*)&wp1, (void*)&h0, (void*)&h1,
                      (void*)&bih0, (void*)&bhh0, (void*)&bih1, (void*)&bhh1,
                      (void*)&out, (void*)&bar };
    hipError_t ce = hipLaunchCooperativeKernel((const void*)lstm_persist,
                                               dim3(128), dim3(512), kargs, 0u, stream);
    if (ce != hipSuccess) {
        // fallback: plain launch (128 blocks on 256 CUs — co-resident)
        lstm_persist<<<128, 512, 0, stream>>>(xbf, wp0, wp1, h0, h1,
                                              bih0, bhh0, bih1, bhh1, out, bar);
    }

    // hidden[1] = h1T lives at float offset 16785408 + 64*512
    out_gemm<<<64, 128, 0, stream>>>(out + 16785408 + BH_, wout, bout, out);
}